// Round 8
// baseline (321.964 us; speedup 1.0000x reference)
//
#include <hip/hip_runtime.h>

// DeltaNet chunkwise delta rule. b=2,h=8,L=4096,d=128,chunk=32.
// R12: R11's consumer load-phase, delivered on R10's proven 3-slab structure
// (R11's 4-slab + runtime dostage rotation hit a gfx950 backend bug:
// V_CMP_NE_U32 $src_shared_base addrspacecast null-check).
//  - compute_chunk: batch-issue ALL 42 LDS reads into named regs; mk_bop x8
//    (VALU) overlaps the wait-train; sched_barrier(0) pins the region.
//  - U accumulation: 4 independent 2-deep MFMA chains + add tree.
//  - S updates before final O MFMAs. Everything else == R10.

#define Bb 2
#define Hh 8
#define Ll 4096
#define Dd 128
#define DP (Dd + 4)
#define Cc 32
#define CP2 33
#define NC (Ll / Cc)       // 128 chunks
#define BHn (Bb * Hh)      // 16 heads

// slab layout (bytes): 0 Wb[16][32]bf16x8=8192 | 8192 Ktb=8192 |
//   16384 Qnb=8192 | 24576 At[4][32]=2048 | 26624 U[32][32]f32=4096
#define SLAB 30720

typedef float  f32x16 __attribute__((ext_vector_type(16)));
typedef short  bf16x8 __attribute__((ext_vector_type(8)));

#define WAITVM(N) asm volatile("s_waitcnt vmcnt(" #N ")" ::: "memory")

__device__ __forceinline__ short f2bf(float x) {
    union { float f; unsigned u; } a; a.f = x;
    const unsigned r = a.u + 0x7FFFu + ((a.u >> 16) & 1u);  // RNE
    return (short)(r >> 16);
}

__device__ __forceinline__ float bf2f(short h) {
    union { unsigned u; float f; } t;
    t.u = ((unsigned)(unsigned short)h) << 16;
    return t.f;
}

__device__ __forceinline__ unsigned cvt_pk_bf16(float lo, float hi) {
    unsigned r;
    asm("v_cvt_pk_bf16_f32 %0, %1, %2" : "=v"(r) : "v"(lo), "v"(hi));
    return r;
}

// C-layout quadrant -> MFMA B-operand fragment for K=16 slice m, via
// v_cvt_pk_bf16_f32 + v_permlane32_swap (VALU only). Proven R5-R10.
__device__ __forceinline__ bf16x8 mk_bop(const f32x16& T, int m) {
    const int o = 8 * m;
    const unsigned a01 = cvt_pk_bf16(T[o + 0], T[o + 1]);
    const unsigned a23 = cvt_pk_bf16(T[o + 2], T[o + 3]);
    const unsigned b01 = cvt_pk_bf16(T[o + 4], T[o + 5]);
    const unsigned b23 = cvt_pk_bf16(T[o + 6], T[o + 7]);
    const auto r0 = __builtin_amdgcn_permlane32_swap(a01, b01, false, false);
    const auto r1 = __builtin_amdgcn_permlane32_swap(a23, b23, false, false);
    union { unsigned u[4]; bf16x8 v; } out;
    out.u[0] = r0[0]; out.u[1] = r1[0]; out.u[2] = r0[1]; out.u[3] = r1[1];
    return out.v;
}

__device__ __forceinline__ void gl_lds16(const void* gsrc, void* ldst) {
    __builtin_amdgcn_global_load_lds(
        (const __attribute__((address_space(1))) unsigned int*)gsrc,
        (__attribute__((address_space(3))) unsigned int*)ldst, 16, 0, 0);
}

// split 8 fp32 into bf16 hi + bf16 residual lo (3-term split-MFMA inputs)
__device__ __forceinline__ void split8(const float4& a, const float4& b,
                                       bf16x8& hi, bf16x8& lo) {
    const float x[8] = {a.x, a.y, a.z, a.w, b.x, b.y, b.z, b.w};
    #pragma unroll
    for (int j = 0; j < 8; ++j) {
        const short hs = f2bf(x[j]);
        hi[j] = hs;
        lo[j] = f2bf(x[j] - bf2f(hs));
    }
}

__device__ __forceinline__ void fma4(float4& acc, float s, const float4& x) {
    acc.x += s * x.x; acc.y += s * x.y; acc.z += s * x.z; acc.w += s * x.w;
}

// ---------------------------------------------------------------------------
// Kernel 1: per-(head,chunk) precompute. 2048 blocks x 256. (unchanged R10)
// ---------------------------------------------------------------------------
template <bool QNB>
__global__ __launch_bounds__(256, 4) void prep_kernel(
    const float* __restrict__ q, const float* __restrict__ k,
    const float* __restrict__ v, const float* __restrict__ beta,
    float* __restrict__ wsU, float* __restrict__ wsNq,
    short* __restrict__ wsWb, short* __restrict__ wsKtb,
    short* __restrict__ wsAttnb, short* __restrict__ wsQnb)
{
    __shared__ float sK[Cc][DP];
    __shared__ float sA[Cc][CP2];
    __shared__ float sInv[Cc][CP2];
    __shared__ float sBeta[Cc], sNk[Cc], sNq[Cc];

    const int tid = threadIdx.x;
    const int blk = blockIdx.x;          // bh*NC + ch
    const int bh = blk / NC;
    const int ch = blk % NC;
    const size_t base = (size_t)(bh * Ll + ch * Cc) * Dd;

    for (int e = tid; e < Cc * Dd / 4; e += 256) {
        const int r = e >> 5, c4 = e & 31;
        ((float4*)&sK[r][0])[c4] = ((const float4*)(k + base))[e];
    }
    if (tid < Cc) sBeta[tid] = beta[bh * Ll + ch * Cc + tid];
    __syncthreads();

    {
        const int row = tid >> 2, part = tid & 3;
        float s = 0.f;
        if (row < Cc) {
            const float4* src = (const float4*)&sK[row][0];
            #pragma unroll
            for (int j = 0; j < 8; ++j) {
                const float4 t = src[part + j * 4];
                s += t.x * t.x + t.y * t.y + t.z * t.z + t.w * t.w;
            }
        } else {
            const float4* src =
                (const float4*)(q + base + (size_t)(row - Cc) * Dd);
            #pragma unroll
            for (int j = 0; j < 8; ++j) {
                const float4 t = src[part + j * 4];
                s += t.x * t.x + t.y * t.y + t.z * t.z + t.w * t.w;
            }
        }
        s += __shfl_xor(s, 1);
        s += __shfl_xor(s, 2);
        if (part == 0) {
            const float r = 1.0f / sqrtf(s);
            if (row < Cc) sNk[row] = r; else sNq[row - Cc] = r;
        }
    }
    __syncthreads();

    if (tid < Cc) wsNq[bh * Ll + ch * Cc + tid] = sNq[tid];

    for (int e = tid; e < Cc * Dd / 4; e += 256) {
        const int r = e >> 5, c4 = e & 31;
        float4 kk = ((float4*)&sK[r][0])[c4];
        const float nk = sNk[r];
        kk.x *= nk; kk.y *= nk; kk.z *= nk; kk.w *= nk;
        ((float4*)&sK[r][0])[c4] = kk;
    }
    __syncthreads();

    const int wid = tid >> 6;
    const int lc = tid & 31;
    const int lh = (tid >> 5) & 1;
    const size_t cbase = (size_t)blk * Cc * Dd;
    const size_t abase = (size_t)blk * Cc * Cc;

    if (wid == 0) {
        f32x16 D, D2;
        #pragma unroll
        for (int r = 0; r < 16; ++r) { D[r] = 0.f; D2[r] = 0.f; }
        #pragma unroll
        for (int ks = 0; ks < 8; ++ks) {
            const float4 a = ((const float4*)&sK[lc][0])[4 * ks + 2 * lh];
            const float4 b = ((const float4*)&sK[lc][0])[4 * ks + 2 * lh + 1];
            bf16x8 hi, lo;
            split8(a, b, hi, lo);
            D  = __builtin_amdgcn_mfma_f32_32x32x16_bf16(hi, hi, D,  0, 0, 0);
            D2 = __builtin_amdgcn_mfma_f32_32x32x16_bf16(hi, lo, D2, 0, 0, 0);
            D2 = __builtin_amdgcn_mfma_f32_32x32x16_bf16(lo, hi, D2, 0, 0, 0);
        }
        #pragma unroll
        for (int r = 0; r < 16; ++r) {
            const int row = (r & 3) + 8 * (r >> 2) + 4 * lh;
            sA[row][lc] = (D[r] + D2[r]) * sBeta[row];
        }
        asm volatile("s_waitcnt lgkmcnt(0)" ::: "memory");
        __builtin_amdgcn_sched_barrier(0);

        float inv[Cc];
        #pragma unroll
        for (int m = 0; m < Cc; ++m) inv[m] = (m == lc) ? 1.f : 0.f;
        #pragma unroll
        for (int i = 1; i < Cc; ++i) {
            float s = 0.f;
            #pragma unroll
            for (int m = 0; m < i; ++m) s += sA[i][m] * inv[m];
            inv[i] = (lc == i) ? 1.f : -s;
        }
        if (lh == 0) {
            #pragma unroll
            for (int m = 0; m < Cc; ++m) sInv[m][lc] = inv[m];
        }
    } else if (wid == 1) {
        const float nq = sNq[lc];
        const float* qrow = q + base + (size_t)lc * Dd;
        f32x16 D, D2;
        #pragma unroll
        for (int r = 0; r < 16; ++r) { D[r] = 0.f; D2[r] = 0.f; }
        #pragma unroll
        for (int ks = 0; ks < 8; ++ks) {
            float4 a = ((const float4*)qrow)[4 * ks + 2 * lh];
            float4 b = ((const float4*)qrow)[4 * ks + 2 * lh + 1];
            a.x *= nq; a.y *= nq; a.z *= nq; a.w *= nq;
            b.x *= nq; b.y *= nq; b.z *= nq; b.w *= nq;
            bf16x8 hiQ, loQ;
            split8(a, b, hiQ, loQ);
            if constexpr (QNB) {
                ((bf16x8*)(wsQnb + cbase))[(2 * ks + lh) * 32 + lc] = hiQ;
            }
            const float4 ka = ((const float4*)&sK[lc][0])[4 * ks + 2 * lh];
            const float4 kb2 = ((const float4*)&sK[lc][0])[4 * ks + 2 * lh + 1];
            bf16x8 hiK, loK;
            split8(ka, kb2, hiK, loK);
            D  = __builtin_amdgcn_mfma_f32_32x32x16_bf16(hiQ, hiK, D,  0, 0, 0);
            D2 = __builtin_amdgcn_mfma_f32_32x32x16_bf16(hiQ, loK, D2, 0, 0, 0);
            D2 = __builtin_amdgcn_mfma_f32_32x32x16_bf16(loQ, hiK, D2, 0, 0, 0);
        }
        #pragma unroll
        for (int r = 0; r < 16; ++r) {
            const int row = (r & 3) + 8 * (r >> 2) + 4 * lh;
            const float val = (lc <= row) ? (D[r] + D2[r]) : 0.f;
            wsAttnb[abase + ((lc >> 3) << 8) + (row << 3) + (lc & 7)] =
                f2bf(val);
        }
    } else {
        const int t = tid - 128;   // 0..127
        #pragma unroll
        for (int it = 0; it < 4; ++it) {
            const int g = t + it * 128;          // 0..511
            const int B = g >> 5, ddl = g & 31;
            const int dd = ((B >> 2) << 5) + ddl;
            const int cc0 = (B & 3) << 3;
            bf16x8 pk;
            #pragma unroll
            for (int j = 0; j < 8; ++j) pk[j] = f2bf(sK[cc0 + j][dd]);
            ((bf16x8*)(wsKtb + cbase))[g] = pk;
        }
    }
    __syncthreads();

    {
        const int c = tid >> 3, g = tid & 7, dd0 = g * 16;
        float4 u0{}, u1{}, u2{}, u3{}, w0{}, w1{}, w2{}, w3{};
        for (int f = 0; f <= c; ++f) {
            const float ivb = sInv[c][f] * sBeta[f];
            const float4* vr = (const float4*)(v + base + (size_t)f * Dd + dd0);
            const float4* kr = (const float4*)&sK[f][dd0];
            fma4(u0, ivb, vr[0]); fma4(u1, ivb, vr[1]);
            fma4(u2, ivb, vr[2]); fma4(u3, ivb, vr[3]);
            fma4(w0, ivb, kr[0]); fma4(w1, ivb, kr[1]);
            fma4(w2, ivb, kr[2]); fma4(w3, ivb, kr[3]);
        }
        // U in C-frag order: [colblk 4][rh 32][col 32] per chunk
        const int rh = (c & 3) + ((c >> 3) << 2) + (((c >> 2) & 1) << 4);
        const float uu[16] = {u0.x, u0.y, u0.z, u0.w, u1.x, u1.y, u1.z, u1.w,
                              u2.x, u2.y, u2.z, u2.w, u3.x, u3.y, u3.z, u3.w};
        #pragma unroll
        for (int j = 0; j < 16; ++j) {
            const int dd = dd0 + j;
            wsU[cbase + ((dd >> 5) << 10) + (rh << 5) + (dd & 31)] = uu[j];
        }
        bf16x8 p0, p1;
        p0[0] = f2bf(-w0.x); p0[1] = f2bf(-w0.y); p0[2] = f2bf(-w0.z);
        p0[3] = f2bf(-w0.w); p0[4] = f2bf(-w1.x); p0[5] = f2bf(-w1.y);
        p0[6] = f2bf(-w1.z); p0[7] = f2bf(-w1.w);
        p1[0] = f2bf(-w2.x); p1[1] = f2bf(-w2.y); p1[2] = f2bf(-w2.z);
        p1[3] = f2bf(-w2.w); p1[4] = f2bf(-w3.x); p1[5] = f2bf(-w3.y);
        p1[6] = f2bf(-w3.z); p1[7] = f2bf(-w3.w);
        ((bf16x8*)(wsWb + cbase))[(2 * g) * 32 + c] = p0;
        ((bf16x8*)(wsWb + cbase))[(2 * g + 1) * 32 + c] = p1;
    }
}

// ---------------------------------------------------------------------------
// Kernel 2: MFMA scan. 64 blocks x 128 threads, 3 slabs (R10 structure).
// Wave 0 = consumer (load-phase then compute). Wave 1 = producer.
// ---------------------------------------------------------------------------
template <bool QNB>
__device__ __forceinline__ void stage_slab(
    char* slab, int bh, int ch, int colBase, int lane,
    const short* __restrict__ wsWb, const short* __restrict__ wsKtb,
    const short* __restrict__ wsQnb, const short* __restrict__ wsAttnb,
    const float* __restrict__ wsU)
{
    const size_t cb = (size_t)(bh * NC + ch) * (Cc * Dd);
    const size_t ab = (size_t)(bh * NC + ch) * (Cc * Cc);
    const char* srcW = (const char*)(wsWb + cb);
    const char* srcK = (const char*)(wsKtb + cb);
    const char* srcA = (const char*)(wsAttnb + ab);
    const int l16 = lane * 16;
    #pragma unroll
    for (int g = 0; g < 8; ++g)
        gl_lds16(srcW + g * 1024 + l16, slab + g * 1024);
    #pragma unroll
    for (int g = 0; g < 8; ++g)
        gl_lds16(srcK + g * 1024 + l16, slab + 8192 + g * 1024);
    if constexpr (QNB) {
        const char* srcQ = (const char*)(wsQnb + cb);
        #pragma unroll
        for (int g = 0; g < 8; ++g)
            gl_lds16(srcQ + g * 1024 + l16, slab + 16384 + g * 1024);
    }
    #pragma unroll
    for (int g = 0; g < 2; ++g)
        gl_lds16(srcA + g * 1024 + l16, slab + 24576 + g * 1024);
    const float* srcU = wsU + cb + (colBase << 5);
    #pragma unroll
    for (int g = 0; g < 4; ++g)
        gl_lds16(srcU + g * 256 + lane * 4, slab + 26624 + g * 1024);
}
// loads per stage: QNB ? 30 : 22

template <bool QNB>
__device__ __forceinline__ void compute_chunk(
    const char* slab, int bh, int ch, int colBase, int c, int h,
    const float* __restrict__ q, const float* __restrict__ wsNq,
    f32x16& S0, f32x16& S1, f32x16& S2, f32x16& S3, float* __restrict__ out)
{
    const bf16x8* Wf = (const bf16x8*)slab;
    const bf16x8* Kf = (const bf16x8*)(slab + 8192);
    const bf16x8* Qf = (const bf16x8*)(slab + 16384);
    const bf16x8* Af = (const bf16x8*)(slab + 24576);
    const float*  Uf = (const float*)(slab + 26624);

    // ---- phase 1: batch-issue ALL operand loads into named registers;
    //      mk_bop x8 (VALU-only) runs under the same wait-train ----
    bf16x8 W[8], K8[8], QA[8], AT[2];
    f32x16 U0;
    #pragma unroll
    for (int ks = 0; ks < 8; ++ks) W[ks] = Wf[(2 * ks + h) * 32 + c];
    #pragma unroll
    for (int j = 0; j < 8; ++j) K8[j] = Kf[(2 * j + h) * 32 + c];
    if constexpr (QNB) {
        #pragma unroll
        for (int ks = 0; ks < 8; ++ks) QA[ks] = Qf[(2 * ks + h) * 32 + c];
    } else {
        const size_t qb = (size_t)(bh * Ll + ch * Cc) * Dd;
        const float rq = wsNq[bh * Ll + ch * Cc + c];
        #pragma unroll
        for (int ks = 0; ks < 8; ++ks) {
            const float4 a = ((const float4*)(q + qb))[c * 32 + 4 * ks + 2 * h];
            const float4 b = ((const float4*)(q + qb))[c * 32 + 4 * ks + 2 * h + 1];
            union { unsigned u[4]; bf16x8 v; } t;
            t.u[0] = cvt_pk_bf16(a.x * rq, a.y * rq);
            t.u[1] = cvt_pk_bf16(a.z * rq, a.w * rq);
            t.u[2] = cvt_pk_bf16(b.x * rq, b.y * rq);
            t.u[3] = cvt_pk_bf16(b.z * rq, b.w * rq);
            QA[ks] = t.v;
        }
    }
    AT[0] = Af[(0 + h) * 32 + c];
    AT[1] = Af[(2 + h) * 32 + c];
    #pragma unroll
    for (int r = 0; r < 16; ++r) U0[r] = Uf[(r + 16 * h) * 32 + c];

    bf16x8 sB[8];
    sB[0] = mk_bop(S0, 0); sB[1] = mk_bop(S0, 1);
    sB[2] = mk_bop(S1, 0); sB[3] = mk_bop(S1, 1);
    sB[4] = mk_bop(S2, 0); sB[5] = mk_bop(S2, 1);
    sB[6] = mk_bop(S3, 0); sB[7] = mk_bop(S3, 1);
    __builtin_amdgcn_sched_barrier(0);

    // ---- phase 2: U accumulation — 4 independent 2-deep chains ----
    f32x16 Ua = U0, Ub, Uc, Ud, O1, O2;
    #pragma unroll
    for (int r = 0; r < 16; ++r) { Ub[r]=0.f; Uc[r]=0.f; Ud[r]=0.f;
                                   O1[r]=0.f; O2[r]=0.f; }
    Ua = __builtin_amdgcn_mfma_f32_32x32x16_bf16(W[0], sB[0], Ua, 0, 0, 0);
    Ub = __builtin_amdgcn_mfma_f32_32x32x16_bf16(W[2], sB[2], Ub, 0, 0, 0);
    Uc = __builtin_amdgcn_mfma_f32_32x32x16_bf16(W[4], sB[4], Uc, 0, 0, 0);
    Ud = __builtin_amdgcn_mfma_f32_32x32x16_bf16(W[6], sB[6], Ud, 0, 0, 0);
    Ua = __builtin_amdgcn_mfma_f32_32x32x16_bf16(W[1], sB[1], Ua, 0, 0, 0);
    Ub = __builtin_amdgcn_mfma_f32_32x32x16_bf16(W[3], sB[3], Ub, 0, 0, 0);
    Uc = __builtin_amdgcn_mfma_f32_32x32x16_bf16(W[5], sB[5], Uc, 0, 0, 0);
    Ud = __builtin_amdgcn_mfma_f32_32x32x16_bf16(W[7], sB[7], Ud, 0, 0, 0);

    // ---- phase 3: O accumulation (independent; fills MFMA pipe) ----
    O1 = __builtin_amdgcn_mfma_f32_32x32x16_bf16(QA[0], sB[0], O1, 0, 0, 0);
    O2 = __builtin_amdgcn_mfma_f32_32x32x16_bf16(QA[1], sB[1], O2, 0, 0, 0);
    O1 = __builtin_amdgcn_mfma_f32_32x32x16_bf16(QA[2], sB[2], O1, 0, 0, 0);
    O2 = __builtin_amdgcn_mfma_f32_32x32x16_bf16(QA[3], sB[3], O2, 0, 0, 0);
    O1 = __builtin_amdgcn_mfma_f32_32x32x16_bf16(QA[4], sB[4], O1, 0, 0, 0);
    O2 = __builtin_amdgcn_mfma_f32_32x32x16_bf16(QA[5], sB[5], O2, 0, 0, 0);
    O1 = __builtin_amdgcn_mfma_f32_32x32x16_bf16(QA[6], sB[6], O1, 0, 0, 0);
    O2 = __builtin_amdgcn_mfma_f32_32x32x16_bf16(QA[7], sB[7], O2, 0, 0, 0);

    // ---- phase 4: combine U, build uB ----
    f32x16 Us;
    #pragma unroll
    for (int r = 0; r < 16; ++r) Us[r] = (Ua[r] + Ub[r]) + (Uc[r] + Ud[r]);
    const bf16x8 uB0 = mk_bop(Us, 0);
    const bf16x8 uB1 = mk_bop(Us, 1);

    // ---- phase 5: S updates first (gate next chunk), then At-O, stores ----
    S0 = __builtin_amdgcn_mfma_f32_32x32x16_bf16(K8[0], uB0, S0, 0, 0, 0);
    S1 = __builtin_amdgcn_mfma_f32_32x32x16_bf16(K8[2], uB0, S1, 0, 0, 0);
    S2 = __builtin_amdgcn_mfma_f32_32x32x16_bf16(K8[4], uB0, S2, 0, 0, 0);
    S3 = __builtin_amdgcn_mfma_f32_32x32x16_bf16(K8[6], uB0, S3, 0, 0, 0);
    S0 = __builtin_amdgcn_mfma_f32_32x32x16_bf16(K8[1], uB1, S0, 0, 0, 0);
    S1 = __builtin_amdgcn_mfma_f32_32x32x16_bf16(K8[3], uB1, S1, 0, 0, 0);
    S2 = __builtin_amdgcn_mfma_f32_32x32x16_bf16(K8[5], uB1, S2, 0, 0, 0);
    S3 = __builtin_amdgcn_mfma_f32_32x32x16_bf16(K8[7], uB1, S3, 0, 0, 0);

    O1 = __builtin_amdgcn_mfma_f32_32x32x16_bf16(AT[0], uB0, O1, 0, 0, 0);
    O2 = __builtin_amdgcn_mfma_f32_32x32x16_bf16(AT[1], uB1, O2, 0, 0, 0);

    const size_t qb = (size_t)(bh * Ll + ch * Cc) * Dd;
    #pragma unroll
    for (int r = 0; r < 16; ++r) {
        const int row = (r & 3) + 8 * (r >> 2) + 4 * h;
        out[qb + (size_t)row * Dd + colBase + c] = O1[r] + O2[r];
    }
}

template <bool QNB>
__device__ __forceinline__ void pcstep(
    int ch, char* cur, char* nxt, bool dostage, int wid,
    int bh, int colBase, int c, int h, int lane,
    const float* __restrict__ q, const float* __restrict__ wsNq,
    const short* __restrict__ wsWb, const short* __restrict__ wsKtb,
    const short* __restrict__ wsAttnb, const short* __restrict__ wsQnb,
    const float* __restrict__ wsU,
    f32x16& S0, f32x16& S1, f32x16& S2, f32x16& S3, float* __restrict__ out)
{
    if (wid == 0) {
        compute_chunk<QNB>(cur, bh, ch, colBase, c, h, q, wsNq,
                           S0, S1, S2, S3, out);
    } else {
        if (dostage) {
            stage_slab<QNB>(nxt, bh, ch + 2, colBase, lane,
                            wsWb, wsKtb, wsQnb, wsAttnb, wsU);
            // counted wait: only stage(ch+1) (issued last step) must be done
            if constexpr (QNB) WAITVM(30); else WAITVM(22);
        } else {
            WAITVM(0);   // epilogue: drain the final outstanding stage
        }
    }
    __builtin_amdgcn_s_barrier();
}

template <bool QNB>
__global__ __launch_bounds__(128, 1) void scan_kernel(
    const float* __restrict__ q, const float* __restrict__ wsU,
    const short* __restrict__ wsWb, const short* __restrict__ wsKtb,
    const short* __restrict__ wsAttnb, const short* __restrict__ wsQnb,
    const float* __restrict__ wsNq, float* __restrict__ out)
{
    __shared__ __attribute__((aligned(16))) char sl0[SLAB];
    __shared__ __attribute__((aligned(16))) char sl1[SLAB];
    __shared__ __attribute__((aligned(16))) char sl2[SLAB];

    const int tid = threadIdx.x;
    const int wid = tid >> 6;       // 0 = consumer, 1 = producer
    const int lane = tid & 63;
    const int h = lane >> 5;
    const int c = lane & 31;
    const int bh = blockIdx.x;
    const int colBase = blockIdx.y * 32;

    f32x16 S0, S1, S2, S3;
    #pragma unroll
    for (int r = 0; r < 16; ++r) { S0[r]=0.f; S1[r]=0.f; S2[r]=0.f; S3[r]=0.f; }

    if (wid == 1) {
        stage_slab<QNB>(sl0, bh, 0, colBase, lane, wsWb, wsKtb, wsQnb,
                        wsAttnb, wsU);
        stage_slab<QNB>(sl1, bh, 1, colBase, lane, wsWb, wsKtb, wsQnb,
                        wsAttnb, wsU);
        // need stage(0) complete; stage(1) may remain in flight
        if constexpr (QNB) WAITVM(30); else WAITVM(22);
    }
    __builtin_amdgcn_s_barrier();

    #pragma unroll 1
    for (int it = 0; it < 42; ++it) {
        const int ch = it * 3;
        pcstep<QNB>(ch + 0, sl0, sl2, true, wid, bh, colBase, c, h, lane,
                    q, wsNq, wsWb, wsKtb, wsAttnb, wsQnb, wsU,
                    S0, S1, S2, S3, out);
        pcstep<QNB>(ch + 1, sl1, sl0, true, wid, bh, colBase, c, h, lane,
                    q, wsNq, wsWb, wsKtb, wsAttnb, wsQnb, wsU,
                    S0, S1, S2, S3, out);
        pcstep<QNB>(ch + 2, sl2, sl1, true, wid, bh, colBase, c, h, lane,
                    q, wsNq, wsWb, wsKtb, wsAttnb, wsQnb, wsU,
                    S0, S1, S2, S3, out);
    }
    // tail: chunks 126 (sl0) and 127 (sl1), no staging
    pcstep<QNB>(126, sl0, sl2, false, wid, bh, colBase, c, h, lane,
                q, wsNq, wsWb, wsKtb, wsAttnb, wsQnb, wsU, S0, S1, S2, S3, out);
    pcstep<QNB>(127, sl1, sl0, false, wid, bh, colBase, c, h, lane,
                q, wsNq, wsWb, wsKtb, wsAttnb, wsQnb, wsU, S0, S1, S2, S3, out);

    // S_final -> d_out tail (consumer only)
    if (wid == 0) {
        const size_t soff = (size_t)Bb * Hh * Ll * Dd;
        #pragma unroll
        for (int t = 0; t < 4; ++t) {
            const f32x16& T = (t == 0) ? S0 : (t == 1) ? S1 : (t == 2) ? S2 : S3;
            #pragma unroll
            for (int r = 0; r < 16; ++r) {
                const int row = 32 * t + (r & 3) + 8 * (r >> 2) + 4 * h;
                out[soff + (size_t)bh * Dd * Dd + (size_t)row * Dd + colBase + c]
                    = T[r];
            }
        }
    }
}

extern "C" void kernel_launch(void* const* d_in, const int* in_sizes, int n_in,
                              void* d_out, int out_size, void* d_ws,
                              size_t ws_size, hipStream_t stream) {
    const float* q    = (const float*)d_in[0];
    const float* k    = (const float*)d_in[1];
    const float* v    = (const float*)d_in[2];
    const float* beta = (const float*)d_in[3];
    float* out = (float*)d_out;

    const size_t nQK = (size_t)BHn * Ll * Dd;          // 8,388,608
    float* wsU    = (float*)d_ws;                      // fp32, 32 MB
    float* wsNq   = wsU + nQK;                         // fp32, 0.25 MB
    short* wsWb   = (short*)(wsNq + (size_t)BHn * Ll); // bf16, 16 MB
    short* wsKtb  = wsWb + nQK;                        // bf16, 16 MB
    short* wsAttnb = wsKtb + nQK;                      // bf16, 4 MB
    short* wsQnb  = wsAttnb + (size_t)BHn * NC * Cc * Cc; // bf16, 16 MB (opt)
    const size_t need_qnb = (size_t)((char*)(wsQnb + nQK) - (char*)d_ws);

    if (ws_size >= need_qnb) {
        prep_kernel<true><<<dim3(BHn * NC), 256, 0, stream>>>(
            q, k, v, beta, wsU, wsNq, wsWb, wsKtb, wsAttnb, wsQnb);
        scan_kernel<true><<<dim3(BHn, 4), 128, 0, stream>>>(
            q, wsU, wsWb, wsKtb, wsAttnb, wsQnb, wsNq, out);
    } else {
        prep_kernel<false><<<dim3(BHn * NC), 256, 0, stream>>>(
            q, k, v, beta, wsU, wsNq, wsWb, wsKtb, wsAttnb, wsQnb);
        scan_kernel<false><<<dim3(BHn, 4), 128, 0, stream>>>(
            q, wsU, wsWb, wsKtb, wsAttnb, wsQnb, wsNq, out);
    }
}